// Round 3
// baseline (1385.168 us; speedup 1.0000x reference)
//
#include <hip/hip_runtime.h>

#define EPS_C 0.05f
#define BLOCK 256
#define ITEMS 16               /* 64 B contiguous per thread (4 x int4) */
#define CHUNK (BLOCK * ITEMS)  /* 4096 */

#define FLAG_AGG 1u
#define FLAG_PRE 2u

__device__ __forceinline__ unsigned long long pack_state(unsigned int flag, float v) {
  return ((unsigned long long)flag << 32) | (unsigned long long)__float_as_uint(v);
}

__device__ __forceinline__ float wave_reduce(float c) {
#pragma unroll
  for (int off = 32; off >= 1; off >>= 1) c += __shfl_down(c, off, 64);
  return c;  // valid in lane 0
}

// Build the 6-entry change table into LDS (thread 0 only; caller syncs).
__device__ __forceinline__ void build_table(const float* bd_p, const float* d_p,
                                            const float* s_p, const float* inc_p,
                                            const float* bi_p, float* cs) {
  if (threadIdx.x == 0) {
    float bd = *bd_p, d = *d_p, s = *s_p, inc = *inc_p, bi = *bi_p;
    cs[0] = 0.0f;                                       // cat 0 (unused)
    cs[1] = fminf(bd, fminf(0.0f, d)) - EPS_C;          // big decrease
    cs[2] = fminf(fmaxf(d, bd + EPS_C), -EPS_C);        // decrease (clip)
    cs[3] = s;                                          // same
    cs[4] = fminf(fmaxf(inc, EPS_C), bi - EPS_C);       // increase (clip)
    cs[5] = fmaxf(bi, fmaxf(0.0f, inc) + EPS_C);        // big increase
    cs[6] = 0.0f; cs[7] = 0.0f;
  }
}

__global__ void k_init(unsigned int* ticket) { *ticket = 0u; }

// Single-pass decoupled-lookback scan.
// states[vb] poison 0xAAAAAAAA.. reads as "not ready" (flag hi-word not 1/2).
__global__ __launch_bounds__(BLOCK) void k_scan_lookback(
    const int* __restrict__ ann, const float* origin, const float* bd,
    const float* d, const float* s, const float* inc, const float* bi,
    unsigned long long* __restrict__ states, unsigned int* __restrict__ ticket,
    float* __restrict__ out, int nb) {
  __shared__ float cs[8];
  __shared__ float wsum[BLOCK / 64];
  __shared__ unsigned int s_vb;
  __shared__ float s_prev;

  build_table(bd, d, s, inc, bi, cs);
  if (threadIdx.x == 0) s_vb = atomicAdd(ticket, 1u);  // virtual block id
  __syncthreads();

  const int vb = (int)s_vb;
  const int t = threadIdx.x;
  const int lane = t & 63, wid = t >> 6;
  const size_t base = (size_t)vb * CHUNK;

  // Load + decode 16 elements (4 consecutive int4 per thread).
  const int4* in4 = (const int4*)(ann + base);
  float vals[ITEMS];
#pragma unroll
  for (int i = 0; i < ITEMS / 4; ++i) {
    int4 v = in4[t * (ITEMS / 4) + i];
    vals[i * 4 + 0] = cs[v.x];
    vals[i * 4 + 1] = cs[v.y];
    vals[i * 4 + 2] = cs[v.z];
    vals[i * 4 + 3] = cs[v.w];
  }
  float run = 0.0f;
#pragma unroll
  for (int i = 0; i < ITEMS; ++i) run += vals[i];

  // Block scan of per-thread totals.
  float x = run;
#pragma unroll
  for (int off = 1; off < 64; off <<= 1) {
    float y = __shfl_up(x, off, 64);
    if (lane >= off) x += y;
  }
  if (lane == 63) wsum[wid] = x;
  __syncthreads();
  float wexcl = 0.0f, tot = 0.0f;
#pragma unroll
  for (int i = 0; i < BLOCK / 64; ++i) {
    float w = wsum[i];
    if (i < wid) wexcl += w;
    tot += w;
  }
  const float texcl = wexcl + (x - run);  // thread-exclusive prefix in block

  // Publish aggregate (or prefix for tile 0) so successors can proceed.
  if (t == 0) {
    unsigned long long st = (vb == 0) ? pack_state(FLAG_PRE, tot)
                                      : pack_state(FLAG_AGG, tot);
    __hip_atomic_store(&states[vb], st, __ATOMIC_RELEASE, __HIP_MEMORY_SCOPE_AGENT);
  }

  // Wave-windowed lookback (wave 0 only).
  if (vb > 0 && wid == 0) {
    float excl = 0.0f;
    int w = vb - 1;
    for (;;) {
      int idx = w - lane;
      unsigned long long st =
          (idx >= 0)
              ? __hip_atomic_load(&states[idx], __ATOMIC_ACQUIRE, __HIP_MEMORY_SCOPE_AGENT)
              : pack_state(FLAG_PRE, 0.0f);  // virtual prefix 0 below tile 0
      unsigned int flag = (unsigned int)(st >> 32);
      float val = __uint_as_float((unsigned int)st);
      bool isP = (flag == FLAG_PRE);
      bool isA = (flag == FLAG_AGG);
      unsigned long long pmask = __ballot(isP);
      unsigned long long nmask = __ballot(!(isP || isA));
      int lp = pmask ? (__ffsll((long long)pmask) - 1) : 64;
      int ln = nmask ? (__ffsll((long long)nmask) - 1) : 64;
      if (lp < ln) {
        // Prefix visible before any not-ready: consume aggs below it + prefix.
        float c = (lane < lp && isA) ? val : ((lane == lp) ? val : 0.0f);
        c = wave_reduce(c);
        excl += __shfl(c, 0, 64);
        break;
      } else if (ln == 64) {
        // Full window of aggregates: consume all 64, slide down.
        float c = wave_reduce(val);
        excl += __shfl(c, 0, 64);
        w -= 64;
      }
      // else: a not-ready blocks the head — spin-retry.
    }
    if (lane == 0) {
      s_prev = excl;
      __hip_atomic_store(&states[vb], pack_state(FLAG_PRE, excl + tot),
                         __ATOMIC_RELEASE, __HIP_MEMORY_SCOPE_AGENT);
    }
  } else if (vb == 0 && t == 0) {
    s_prev = 0.0f;
  }
  __syncthreads();

  const float off0 = *origin + s_prev + texcl;

  // Write 16 outputs per thread (out[j] = origin + exclusive_prefix(j)).
  float4* out4 = (float4*)(out + base);
  float r = off0;
#pragma unroll
  for (int i = 0; i < ITEMS / 4; ++i) {
    float4 o;
    o.x = r; r += vals[i * 4 + 0];
    o.y = r; r += vals[i * 4 + 1];
    o.z = r; r += vals[i * 4 + 2];
    o.w = r; r += vals[i * 4 + 3];
    out4[t * (ITEMS / 4) + i] = o;
  }
  if (vb == nb - 1 && t == BLOCK - 1)
    out[(size_t)nb * CHUNK] = r;  // out[N] = origin + total sum
}

extern "C" void kernel_launch(void* const* d_in, const int* in_sizes, int n_in,
                              void* d_out, int out_size, void* d_ws, size_t ws_size,
                              hipStream_t stream) {
  const int*   ann    = (const int*)d_in[0];
  const float* origin = (const float*)d_in[1];
  const float* bd     = (const float*)d_in[2];
  const float* dw     = (const float*)d_in[3];
  const float* sw     = (const float*)d_in[4];
  const float* inc    = (const float*)d_in[5];
  const float* bi     = (const float*)d_in[6];
  float* out = (float*)d_out;

  const int N  = in_sizes[0];   // 2^25, divisible by CHUNK
  const int nb = N / CHUNK;     // 8192 tiles

  unsigned int* ticket = (unsigned int*)d_ws;                    // 8 B slot
  unsigned long long* states = (unsigned long long*)((char*)d_ws + 8);  // nb * 8 B

  k_init<<<1, 1, 0, stream>>>(ticket);
  k_scan_lookback<<<nb, BLOCK, 0, stream>>>(ann, origin, bd, dw, sw, inc, bi,
                                            states, ticket, out, nb);
}

// Round 4
// 495.631 us; speedup vs baseline: 2.7948x; 2.7948x over previous
//
#include <hip/hip_runtime.h>
#include <hip/hip_cooperative_groups.h>

namespace cg = cooperative_groups;

#define EPS_C 0.05f
#define BLOCK 256
#define GRID_G 1024            /* co-resident blocks (4/CU, tiny kernel) */
#define TILE 4096              /* elems per block-iteration (16/thread) */
#define ITERS 8                /* (N/GRID_G)/TILE = 32768/4096 */

// Single cooperative kernel:
//  Phase 1: read span once, pack categories (4b/elem) into LDS, publish span sum.
//  grid.sync()
//  Phase 2: block offset = sum of predecessor sums; decode LDS, scan, write.
__global__ __launch_bounds__(BLOCK) void k_coop_scan(
    const int* __restrict__ ann, const float* __restrict__ origin,
    const float* __restrict__ bd, const float* __restrict__ d,
    const float* __restrict__ s, const float* __restrict__ inc,
    const float* __restrict__ bi, float* __restrict__ ws_sums,
    float* __restrict__ out, int N) {
  __shared__ float cs[8];
  __shared__ float wsum[BLOCK / 64];
  __shared__ float s_base;
  __shared__ unsigned int pack[ITERS * BLOCK * 2];  // 16 KB

  if (threadIdx.x == 0) {
    float bdv = *bd, dv = *d, sv = *s, incv = *inc, biv = *bi;
    cs[0] = 0.0f;                                        // cat 0 (unused)
    cs[1] = fminf(bdv, fminf(0.0f, dv)) - EPS_C;         // big decrease
    cs[2] = fminf(fmaxf(dv, bdv + EPS_C), -EPS_C);       // decrease (clip)
    cs[3] = sv;                                          // same
    cs[4] = fminf(fmaxf(incv, EPS_C), biv - EPS_C);      // increase (clip)
    cs[5] = fmaxf(biv, fmaxf(0.0f, incv) + EPS_C);       // big increase
    cs[6] = 0.0f; cs[7] = 0.0f;
  }
  __syncthreads();

  const int b = blockIdx.x, t = threadIdx.x;
  const int lane = t & 63, wid = t >> 6;
  const int S = N / GRID_G;          // 32768 elems per block
  const size_t base0 = (size_t)b * S;

  // ---- Phase 1: load once, pack to LDS, accumulate block sum ----
  float bsum = 0.0f;
  for (int it = 0; it < ITERS; ++it) {
    const int4* in4 = (const int4*)(ann + base0 + (size_t)it * TILE);
    unsigned int w[2] = {0u, 0u};
    float ssum = 0.0f;
#pragma unroll
    for (int i = 0; i < 4; ++i) {
      int4 v = in4[t * 4 + i];
      ssum += cs[v.x] + cs[v.y] + cs[v.z] + cs[v.w];
      unsigned int nib = (unsigned)v.x | ((unsigned)v.y << 4) |
                         ((unsigned)v.z << 8) | ((unsigned)v.w << 12);
      w[i >> 1] |= nib << ((i & 1) * 16);
    }
    pack[(it * BLOCK + t) * 2 + 0] = w[0];
    pack[(it * BLOCK + t) * 2 + 1] = w[1];
    bsum += ssum;
  }
#pragma unroll
  for (int off = 32; off >= 1; off >>= 1) bsum += __shfl_down(bsum, off, 64);
  if (lane == 0) wsum[wid] = bsum;
  __syncthreads();
  if (t == 0) {
    float tot = wsum[0] + wsum[1] + wsum[2] + wsum[3];
    __hip_atomic_store(&ws_sums[b], tot, __ATOMIC_RELEASE,
                       __HIP_MEMORY_SCOPE_AGENT);
  }

  cg::this_grid().sync();

  // ---- Phase 2a: block offset = origin + sum of ws_sums[0..b) ----
  float p = 0.0f;
  for (int i = t; i < b; i += BLOCK)
    p += __hip_atomic_load(&ws_sums[i], __ATOMIC_ACQUIRE,
                           __HIP_MEMORY_SCOPE_AGENT);
#pragma unroll
  for (int off = 32; off >= 1; off >>= 1) p += __shfl_down(p, off, 64);
  if (lane == 0) wsum[wid] = p;
  __syncthreads();
  if (t == 0) s_base = *origin + wsum[0] + wsum[1] + wsum[2] + wsum[3];
  __syncthreads();

  // ---- Phase 2b: decode from LDS, block-scan each tile, write ----
  float carry = s_base;
  for (int it = 0; it < ITERS; ++it) {
    unsigned int w0 = pack[(it * BLOCK + t) * 2 + 0];
    unsigned int w1 = pack[(it * BLOCK + t) * 2 + 1];
    float vals[16];
#pragma unroll
    for (int j = 0; j < 8; ++j) vals[j] = cs[(w0 >> (4 * j)) & 0xF];
#pragma unroll
    for (int j = 0; j < 8; ++j) vals[8 + j] = cs[(w1 >> (4 * j)) & 0xF];

    float run = 0.0f;
#pragma unroll
    for (int i = 0; i < 16; ++i) run += vals[i];

    float x = run;  // inclusive wave scan of per-thread totals
#pragma unroll
    for (int off = 1; off < 64; off <<= 1) {
      float y = __shfl_up(x, off, 64);
      if (lane >= off) x += y;
    }
    __syncthreads();  // prior iteration's wsum reads are done
    if (lane == 63) wsum[wid] = x;
    __syncthreads();
    float wexcl = 0.0f, tot = 0.0f;
#pragma unroll
    for (int i = 0; i < BLOCK / 64; ++i) {
      float wv = wsum[i];
      if (i < wid) wexcl += wv;
      tot += wv;
    }
    const float off0 = carry + wexcl + (x - run);  // thread-exclusive prefix

    float4* out4 = (float4*)(out + base0 + (size_t)it * TILE);
    float r = off0;
#pragma unroll
    for (int i = 0; i < 4; ++i) {
      float4 o;
      o.x = r; r += vals[i * 4 + 0];
      o.y = r; r += vals[i * 4 + 1];
      o.z = r; r += vals[i * 4 + 2];
      o.w = r; r += vals[i * 4 + 3];
      out4[t * 4 + i] = o;
    }
    carry += tot;
  }

  if (b == GRID_G - 1 && t == BLOCK - 1)
    out[N] = carry;  // out[N] = origin + total sum
}

extern "C" void kernel_launch(void* const* d_in, const int* in_sizes, int n_in,
                              void* d_out, int out_size, void* d_ws, size_t ws_size,
                              hipStream_t stream) {
  const int*   ann    = (const int*)d_in[0];
  const float* origin = (const float*)d_in[1];
  const float* bd     = (const float*)d_in[2];
  const float* dw     = (const float*)d_in[3];
  const float* sw     = (const float*)d_in[4];
  const float* inc    = (const float*)d_in[5];
  const float* bi     = (const float*)d_in[6];
  float* out = (float*)d_out;
  float* ws_sums = (float*)d_ws;   // GRID_G floats
  int N = in_sizes[0];             // 2^25, divisible by GRID_G*TILE

  void* args[] = {(void*)&ann, (void*)&origin, (void*)&bd, (void*)&dw,
                  (void*)&sw,  (void*)&inc,    (void*)&bi, (void*)&ws_sums,
                  (void*)&out, (void*)&N};
  hipLaunchCooperativeKernel((const void*)k_coop_scan, dim3(GRID_G),
                             dim3(BLOCK), args, 0, stream);
}

// Round 5
// 274.083 us; speedup vs baseline: 5.0538x; 1.8083x over previous
//
#include <hip/hip_runtime.h>

#define EPS_C 0.05f
#define BLOCK 256
#define CHUNK 4096   /* elems per block: 16 per thread */

// Build the 6-entry change table into LDS (thread 0 only; caller syncs).
__device__ __forceinline__ void build_table(const float* bd_p, const float* d_p,
                                            const float* s_p, const float* inc_p,
                                            const float* bi_p, float* cs) {
  if (threadIdx.x == 0) {
    float bd = *bd_p, d = *d_p, s = *s_p, inc = *inc_p, bi = *bi_p;
    cs[0] = 0.0f;                                       // cat 0 (unused)
    cs[1] = fminf(bd, fminf(0.0f, d)) - EPS_C;          // big decrease
    cs[2] = fminf(fmaxf(d, bd + EPS_C), -EPS_C);        // decrease (clip)
    cs[3] = s;                                          // same
    cs[4] = fminf(fmaxf(inc, EPS_C), bi - EPS_C);       // increase (clip)
    cs[5] = fmaxf(bi, fmaxf(0.0f, inc) + EPS_C);        // big increase
    cs[6] = 0.0f; cs[7] = 0.0f;
  }
}

// Pass 1: per-block sum + re-pack categories to 4 bits/elem in global ws.
// Thread t handles elems [b*4096 + t*16, +16): reads 4 int4 (64 B),
// writes one uint2 (8 B packed) — both coalesced.
__global__ __launch_bounds__(BLOCK) void k_reduce_pack(
    const int* __restrict__ ann, const float* bd, const float* d,
    const float* s, const float* inc, const float* bi,
    uint2* __restrict__ packed, float* __restrict__ sums) {
  __shared__ float cs[8];
  __shared__ float wsum[BLOCK / 64];
  build_table(bd, d, s, inc, bi, cs);
  __syncthreads();

  const int b = blockIdx.x, t = threadIdx.x;
  const int4* in4 = (const int4*)(ann + (size_t)b * CHUNK);

  unsigned int w0 = 0u, w1 = 0u;
  float sum = 0.0f;
#pragma unroll
  for (int i = 0; i < 4; ++i) {
    int4 v = in4[t * 4 + i];
    sum += cs[v.x] + cs[v.y] + cs[v.z] + cs[v.w];
    unsigned int nib = (unsigned)v.x | ((unsigned)v.y << 4) |
                       ((unsigned)v.z << 8) | ((unsigned)v.w << 12);
    if (i < 2) w0 |= nib << ((i & 1) * 16);
    else       w1 |= nib << ((i & 1) * 16);
  }
  packed[(size_t)b * BLOCK + t] = make_uint2(w0, w1);

#pragma unroll
  for (int off = 32; off >= 1; off >>= 1) sum += __shfl_down(sum, off, 64);
  const int lane = t & 63, wid = t >> 6;
  if (lane == 0) wsum[wid] = sum;
  __syncthreads();
  if (t == 0) sums[b] = wsum[0] + wsum[1] + wsum[2] + wsum[3];
}

// Pass 2: block b reduces sums[0..b) (L2-resident, 32 KB max) for its offset,
// decodes its packed tile, block-scans, writes 4096 outputs.
__global__ __launch_bounds__(BLOCK) void k_scan_out(
    const uint2* __restrict__ packed, const float* __restrict__ sums,
    const float* __restrict__ origin, const float* bd, const float* d,
    const float* s, const float* inc, const float* bi,
    float* __restrict__ out, int nb) {
  __shared__ float cs[8];
  __shared__ float wsum[BLOCK / 64];
  __shared__ float s_base;
  build_table(bd, d, s, inc, bi, cs);
  __syncthreads();

  const int b = blockIdx.x, t = threadIdx.x;
  const int lane = t & 63, wid = t >> 6;

  // Block offset: reduce predecessor sums (coalesced, L2-hot).
  float p = 0.0f;
  for (int i = t; i < b; i += BLOCK) p += sums[i];
#pragma unroll
  for (int off = 32; off >= 1; off >>= 1) p += __shfl_down(p, off, 64);
  if (lane == 0) wsum[wid] = p;
  __syncthreads();
  if (t == 0) s_base = *origin + wsum[0] + wsum[1] + wsum[2] + wsum[3];
  __syncthreads();

  // Decode 16 categories from one uint2.
  uint2 w = packed[(size_t)b * BLOCK + t];
  float vals[16];
#pragma unroll
  for (int j = 0; j < 8; ++j) vals[j] = cs[(w.x >> (4 * j)) & 0xF];
#pragma unroll
  for (int j = 0; j < 8; ++j) vals[8 + j] = cs[(w.y >> (4 * j)) & 0xF];

  float run = 0.0f;
#pragma unroll
  for (int i = 0; i < 16; ++i) run += vals[i];

  float x = run;  // inclusive wave scan of per-thread totals
#pragma unroll
  for (int off = 1; off < 64; off <<= 1) {
    float y = __shfl_up(x, off, 64);
    if (lane >= off) x += y;
  }
  __syncthreads();  // s_base/wsum reads above are done
  if (lane == 63) wsum[wid] = x;
  __syncthreads();
  float wexcl = 0.0f;
#pragma unroll
  for (int i = 0; i < BLOCK / 64; ++i)
    if (i < wid) wexcl += wsum[i];

  const float off0 = s_base + wexcl + (x - run);  // thread-exclusive prefix

  const size_t base = (size_t)b * CHUNK;
  float4* out4 = (float4*)(out + base);
  float r = off0;
#pragma unroll
  for (int i = 0; i < 4; ++i) {
    float4 o;
    o.x = r; r += vals[i * 4 + 0];
    o.y = r; r += vals[i * 4 + 1];
    o.z = r; r += vals[i * 4 + 2];
    o.w = r; r += vals[i * 4 + 3];
    out4[t * 4 + i] = o;
  }
  if (b == nb - 1 && t == BLOCK - 1)
    out[(size_t)nb * CHUNK] = r;  // out[N] = origin + total sum
}

extern "C" void kernel_launch(void* const* d_in, const int* in_sizes, int n_in,
                              void* d_out, int out_size, void* d_ws, size_t ws_size,
                              hipStream_t stream) {
  const int*   ann    = (const int*)d_in[0];
  const float* origin = (const float*)d_in[1];
  const float* bd     = (const float*)d_in[2];
  const float* dw     = (const float*)d_in[3];
  const float* sw     = (const float*)d_in[4];
  const float* inc    = (const float*)d_in[5];
  const float* bi     = (const float*)d_in[6];
  float* out = (float*)d_out;

  const int N  = in_sizes[0];   // 2^25, divisible by CHUNK
  const int nb = N / CHUNK;     // 8192

  float* sums   = (float*)d_ws;                          // nb floats (32 KB)
  uint2* packed = (uint2*)((char*)d_ws + 32768);         // nb*256 uint2 (16.8 MB)

  k_reduce_pack<<<nb, BLOCK, 0, stream>>>(ann, bd, dw, sw, inc, bi, packed, sums);
  k_scan_out<<<nb, BLOCK, 0, stream>>>(packed, sums, origin, bd, dw, sw, inc, bi,
                                       out, nb);
}